// Round 1
// baseline (32.680 us; speedup 1.0000x reference)
//
#include <hip/hip_runtime.h>

#define NQ 20

// ---------- per-row helpers (all weights in registers, fully unrolled) ----------

// Monotone head with temp == 0:
//   h0 = relu(q*base) = q*relu(base)  (exact, q >= 0)
//   => h1 pre-act = q*c_k + bs1_k with c_k = sum_h relu(base_h)*ws1[h][k]
__device__ __forceinline__ float mono_zero(
    float xt, const float wd[4], const float ws1[16], const float bs1[4],
    const float wl[4], float bl, float step)
{
    float c[4] = {0.f, 0.f, 0.f, 0.f};
#pragma unroll
    for (int h = 0; h < 4; ++h) {
        float rb = fmaxf(xt * wd[h], 0.f);
#pragma unroll
        for (int k = 0; k < 4; ++k) c[k] = fmaf(rb, ws1[h * 4 + k], c[k]);
    }
    float acc = 0.f;
#pragma unroll
    for (int qi = 0; qi < NQ; ++qi) {
        float q = (float)qi * step;
        float f = bl;
#pragma unroll
        for (int k = 0; k < 4; ++k) {
            float v = fmaxf(fmaf(q, c[k], bs1[k]), 0.f);
            f = fmaf(v, wl[k], f);
        }
        acc = fmaf(f, f, acc);
    }
    return acc * step * xt;
}

// Monotone head with per-row temp[4].
__device__ __forceinline__ float mono_temp(
    float xt, const float temp[4], const float wd[4], const float ws1[16],
    const float bs1[4], const float wl[4], float bl, float step)
{
    float base[4];
#pragma unroll
    for (int h = 0; h < 4; ++h) base[h] = xt * wd[h];
    float acc = 0.f;
#pragma unroll
    for (int qi = 0; qi < NQ; ++qi) {
        float q = (float)qi * step;
        float h0[4];
#pragma unroll
        for (int h = 0; h < 4; ++h) h0[h] = fmaxf(fmaf(q, base[h], temp[h]), 0.f);
        float f = bl;
#pragma unroll
        for (int k = 0; k < 4; ++k) {
            float v = bs1[k];
#pragma unroll
            for (int h = 0; h < 4; ++h) v = fmaf(h0[h], ws1[h * 4 + k], v);
            v = fmaxf(v, 0.f);
            f = fmaf(v, wl[k], f);
        }
        acc = fmaf(f, f, acc);
    }
    return acc * step * xt;
}

// Generic 2-4-4-1 MLP.
__device__ __forceinline__ float gen2(
    float x0, float x1, const float ws0[8], const float bs0[4],
    const float ws1[16], const float bs1[4], const float wl[4], float bl)
{
    float h0[4];
#pragma unroll
    for (int j = 0; j < 4; ++j)
        h0[j] = fmaxf(fmaf(x1, ws0[4 + j], fmaf(x0, ws0[j], bs0[j])), 0.f);
    float f = bl;
#pragma unroll
    for (int k = 0; k < 4; ++k) {
        float v = bs1[k];
#pragma unroll
        for (int j = 0; j < 4; ++j) v = fmaf(h0[j], ws1[j * 4 + k], v);
        v = fmaxf(v, 0.f);
        f = fmaf(v, wl[k], f);
    }
    return f;
}

__global__ __launch_bounds__(256) void monotone_fused_kernel(
    const float* __restrict__ x,
    const float* __restrict__ p_m0_wd, const float* __restrict__ p_m0_ws1,
    const float* __restrict__ p_m0_bs1, const float* __restrict__ p_m0_wl,
    const float* __restrict__ p_m0_bl,
    const float* __restrict__ p_m1_wd, const float* __restrict__ p_m1_ws0,
    const float* __restrict__ p_m1_bs0, const float* __restrict__ p_m1_ws1,
    const float* __restrict__ p_m1_bs1, const float* __restrict__ p_m1_wl,
    const float* __restrict__ p_m1_bl,
    const float* __restrict__ p_g0_b,
    const float* __restrict__ p_g1_ws0, const float* __restrict__ p_g1_bs0,
    const float* __restrict__ p_g1_ws1, const float* __restrict__ p_g1_bs1,
    const float* __restrict__ p_g1_wl, const float* __restrict__ p_g1_bl,
    float* __restrict__ out, int nrows)
{
    const int tid = blockIdx.x * blockDim.x + threadIdx.x;
    const int r0 = tid * 2;
    if (r0 >= nrows) return;

    const float step = 1.0f / (float)NQ;

    // ---- load weights (uniform across lanes; cached/broadcast) ----
    float m0_wd[4], m0_ws1[16], m0_bs1[4], m0_wl[4], m0_bl;
    float m1_wd[4], m1_ws0[4], m1_bs0[4], m1_ws1[16], m1_bs1[4], m1_wl[4], m1_bl;
    float g0b;
    float g1_ws0[8], g1_bs0[4], g1_ws1[16], g1_bs1[4], g1_wl[4], g1_bl;

#pragma unroll
    for (int i = 0; i < 4; ++i) {
        m0_wd[i] = p_m0_wd[i];  m0_bs1[i] = p_m0_bs1[i];  m0_wl[i] = p_m0_wl[i];
        m1_wd[i] = p_m1_wd[i];  m1_ws0[i] = p_m1_ws0[i];  m1_bs0[i] = p_m1_bs0[i];
        m1_bs1[i] = p_m1_bs1[i]; m1_wl[i] = p_m1_wl[i];
        g1_bs0[i] = p_g1_bs0[i]; g1_bs1[i] = p_g1_bs1[i]; g1_wl[i] = p_g1_wl[i];
    }
#pragma unroll
    for (int i = 0; i < 16; ++i) { m0_ws1[i] = p_m0_ws1[i]; m1_ws1[i] = p_m1_ws1[i]; g1_ws1[i] = p_g1_ws1[i]; }
#pragma unroll
    for (int i = 0; i < 8; ++i) g1_ws0[i] = p_g1_ws0[i];
    m0_bl = p_m0_bl[0]; m1_bl = p_m1_bl[0]; g0b = p_g0_b[0]; g1_bl = p_g1_bl[0];

    // ---- per-row computation ----
    auto row_compute = [&](float x0, float x1, float& y0, float& y1) {
        y0 = mono_zero(x0, m0_wd, m0_ws1, m0_bs1, m0_wl, m0_bl, step) + g0b;
        float t1[4];
#pragma unroll
        for (int h = 0; h < 4; ++h) t1[h] = fmaf(x0, m1_ws0[h], m1_bs0[h]);
        y1 = mono_temp(x1, t1, m1_wd, m1_ws1, m1_bs1, m1_wl, m1_bl, step)
           + gen2(x0, x1, g1_ws0, g1_bs0, g1_ws1, g1_bs1, g1_wl, g1_bl);
    };

    if (r0 + 1 < nrows) {
        const float4 xin = reinterpret_cast<const float4*>(x)[tid];
        float4 o;
        row_compute(xin.x, xin.y, o.x, o.y);
        row_compute(xin.z, xin.w, o.z, o.w);
        reinterpret_cast<float4*>(out)[tid] = o;
    } else {
        // odd tail row
        const float x0 = x[r0 * 2 + 0];
        const float x1 = x[r0 * 2 + 1];
        float y0, y1;
        row_compute(x0, x1, y0, y1);
        out[r0 * 2 + 0] = y0;
        out[r0 * 2 + 1] = y1;
    }
}

extern "C" void kernel_launch(void* const* d_in, const int* in_sizes, int n_in,
                              void* d_out, int out_size, void* d_ws, size_t ws_size,
                              hipStream_t stream) {
    const float* x       = (const float*)d_in[0];
    const float* m0_wd   = (const float*)d_in[1];
    const float* m0_ws1  = (const float*)d_in[2];
    const float* m0_bs1  = (const float*)d_in[3];
    const float* m0_wl   = (const float*)d_in[4];
    const float* m0_bl   = (const float*)d_in[5];
    const float* m1_wd   = (const float*)d_in[6];
    const float* m1_ws0  = (const float*)d_in[7];
    const float* m1_bs0  = (const float*)d_in[8];
    const float* m1_ws1  = (const float*)d_in[9];
    const float* m1_bs1  = (const float*)d_in[10];
    const float* m1_wl   = (const float*)d_in[11];
    const float* m1_bl   = (const float*)d_in[12];
    const float* g0_b    = (const float*)d_in[13];
    const float* g1_ws0  = (const float*)d_in[14];
    const float* g1_bs0  = (const float*)d_in[15];
    const float* g1_ws1  = (const float*)d_in[16];
    const float* g1_bs1  = (const float*)d_in[17];
    const float* g1_wl   = (const float*)d_in[18];
    const float* g1_bl   = (const float*)d_in[19];
    float* out = (float*)d_out;

    const int nrows  = in_sizes[0] / 2;
    const int npairs = (nrows + 1) / 2;
    const int threads = 256;
    const int blocks  = (npairs + threads - 1) / threads;

    hipLaunchKernelGGL(monotone_fused_kernel, dim3(blocks), dim3(threads), 0, stream,
                       x, m0_wd, m0_ws1, m0_bs1, m0_wl, m0_bl,
                       m1_wd, m1_ws0, m1_bs0, m1_ws1, m1_bs1, m1_wl, m1_bl,
                       g0_b, g1_ws0, g1_bs0, g1_ws1, g1_bs1, g1_wl, g1_bl,
                       out, nrows);
}

// Round 2
// 26.659 us; speedup vs baseline: 1.2259x; 1.2259x over previous
//
#include <hip/hip_runtime.h>

#define NQ 20

typedef float v4f __attribute__((ext_vector_type(4)));

static __device__ __forceinline__ v4f vbc(float s) { return (v4f){s, s, s, s}; }
static __device__ __forceinline__ v4f vfma4(v4f a, v4f b, v4f c) { return __builtin_elementwise_fma(a, b, c); }
static __device__ __forceinline__ v4f vfmab(v4f a, float b, v4f c) { return __builtin_elementwise_fma(a, vbc(b), c); }
static __device__ __forceinline__ v4f vrelu(v4f a) { return __builtin_elementwise_max(a, vbc(0.0f)); }

// Each thread processes 4 rows as lanes of v4f values: rows {2t, 2t+1} from
// x-chunk t and rows {2(t+T), 2(t+T)+1} from x-chunk t+T (two fully coalesced
// float4 streams). All fma/add/mul are v4f -> 2x v_pk_fma_f32 each; relu
// stays scalar v_max_f32.
__global__ __launch_bounds__(256) void monotone_fused_pk(
    const float4* __restrict__ x4,
    const float* __restrict__ p_m0_wd, const float* __restrict__ p_m0_ws1,
    const float* __restrict__ p_m0_bs1, const float* __restrict__ p_m0_wl,
    const float* __restrict__ p_m0_bl,
    const float* __restrict__ p_m1_wd, const float* __restrict__ p_m1_ws0,
    const float* __restrict__ p_m1_bs0, const float* __restrict__ p_m1_ws1,
    const float* __restrict__ p_m1_bs1, const float* __restrict__ p_m1_wl,
    const float* __restrict__ p_m1_bl,
    const float* __restrict__ p_g0_b,
    const float* __restrict__ p_g1_ws0, const float* __restrict__ p_g1_bs0,
    const float* __restrict__ p_g1_ws1, const float* __restrict__ p_g1_bs1,
    const float* __restrict__ p_g1_wl, const float* __restrict__ p_g1_bl,
    float4* __restrict__ out4, int nchunks, int T)
{
    const int t = blockIdx.x * blockDim.x + threadIdx.x;
    if (t >= T) return;

    const float step = 1.0f / (float)NQ;

    // ---- uniform weights (uniform addresses -> s_load; SGPR operands) ----
    float m0_wd[4], m0_ws1[16], m0_bs1[4], m0_wl[4], m0_bl;
    float m1_wd[4], m1_ws0[4], m1_bs0[4], m1_ws1[16], m1_bs1[4], m1_wl[4], m1_bl;
    float g0b;
    float g1_ws0[8], g1_bs0[4], g1_ws1[16], g1_bs1[4], g1_wl[4], g1_bl;

#pragma unroll
    for (int i = 0; i < 4; ++i) {
        m0_wd[i] = p_m0_wd[i];  m0_bs1[i] = p_m0_bs1[i];  m0_wl[i] = p_m0_wl[i];
        m1_wd[i] = p_m1_wd[i];  m1_ws0[i] = p_m1_ws0[i];  m1_bs0[i] = p_m1_bs0[i];
        m1_bs1[i] = p_m1_bs1[i]; m1_wl[i] = p_m1_wl[i];
        g1_bs0[i] = p_g1_bs0[i]; g1_bs1[i] = p_g1_bs1[i]; g1_wl[i] = p_g1_wl[i];
    }
#pragma unroll
    for (int i = 0; i < 16; ++i) { m0_ws1[i] = p_m0_ws1[i]; m1_ws1[i] = p_m1_ws1[i]; g1_ws1[i] = p_g1_ws1[i]; }
#pragma unroll
    for (int i = 0; i < 8; ++i) g1_ws0[i] = p_g1_ws0[i];
    m0_bl = p_m0_bl[0]; m1_bl = p_m1_bl[0]; g0b = p_g0_b[0]; g1_bl = p_g1_bl[0];

    // ---- gather 4 rows ----
    const float4 a = x4[t];
    const bool has2 = (t + T) < nchunks;
    const float4 b = has2 ? x4[t + T] : a;
    v4f x0 = {a.x, a.z, b.x, b.z};
    v4f x1 = {a.y, a.w, b.y, b.w};

    // ---- gen MLP (2-4-4-1) on [x0,x1] ----
    v4f g;
    {
        v4f h0[4];
#pragma unroll
        for (int j = 0; j < 4; ++j)
            h0[j] = vrelu(vfmab(x1, g1_ws0[4 + j], vfmab(x0, g1_ws0[j], vbc(g1_bs0[j]))));
        v4f f = vbc(g1_bl);
#pragma unroll
        for (int k = 0; k < 4; ++k) {
            v4f v = vbc(g1_bs1[k]);
#pragma unroll
            for (int j = 0; j < 4; ++j) v = vfmab(h0[j], g1_ws1[j * 4 + k], v);
            f = vfmab(vrelu(v), g1_wl[k], f);
        }
        g = f;
    }

    // ---- mono head 0 (temp == 0): h0 = relu(q*base) = q*relu(base) ----
    // h1 pre-act = q*c_k + bs1_k; iterate incrementally: v += step*c.
    v4f v0[4], dv0[4];
    {
        v4f c[4] = {vbc(0.f), vbc(0.f), vbc(0.f), vbc(0.f)};
#pragma unroll
        for (int h = 0; h < 4; ++h) {
            v4f rb = vrelu(x0 * vbc(m0_wd[h]));
#pragma unroll
            for (int k = 0; k < 4; ++k) c[k] = vfmab(rb, m0_ws1[h * 4 + k], c[k]);
        }
#pragma unroll
        for (int k = 0; k < 4; ++k) { v0[k] = vbc(m0_bs1[k]); dv0[k] = c[k] * vbc(step); }
    }

    // ---- mono head 1 pre-state: u_h(q) = q*(x1*wd_h) + temp_h, incremental ----
    v4f u[4], du[4];
#pragma unroll
    for (int h = 0; h < 4; ++h) {
        u[h]  = vfmab(x0, m1_ws0[h], vbc(m1_bs0[h]));   // temp1 = x0@ws0 + bs0 (q=0 value)
        du[h] = x1 * vbc(m1_wd[h] * step);
    }

    // ---- merged quadrature loop (both heads; independent chains for ILP) ----
    v4f acc0 = vbc(0.f), acc1 = vbc(0.f);
#pragma unroll
    for (int qi = 0; qi < NQ; ++qi) {
        // head 0
        v4f f0 = vbc(m0_bl);
#pragma unroll
        for (int k = 0; k < 4; ++k) f0 = vfmab(vrelu(v0[k]), m0_wl[k], f0);
        acc0 = vfma4(f0, f0, acc0);

        // head 1
        v4f h0[4];
#pragma unroll
        for (int h = 0; h < 4; ++h) h0[h] = vrelu(u[h]);
        v4f f1 = vbc(m1_bl);
#pragma unroll
        for (int k = 0; k < 4; ++k) {
            v4f vv = vbc(m1_bs1[k]);
#pragma unroll
            for (int h = 0; h < 4; ++h) vv = vfmab(h0[h], m1_ws1[h * 4 + k], vv);
            f1 = vfmab(vrelu(vv), m1_wl[k], f1);
        }
        acc1 = vfma4(f1, f1, acc1);

        if (qi != NQ - 1) {
#pragma unroll
            for (int k = 0; k < 4; ++k) v0[k] = v0[k] + dv0[k];
#pragma unroll
            for (int h = 0; h < 4; ++h) u[h] = u[h] + du[h];
        }
    }

    v4f y0 = (acc0 * vbc(step)) * x0 + vbc(g0b);
    v4f y1 = vfma4(acc1 * vbc(step), x1, g);

    const float4 oa = {y0.x, y1.x, y0.y, y1.y};
    out4[t] = oa;
    if (has2) {
        const float4 ob = {y0.z, y1.z, y0.w, y1.w};
        out4[t + T] = ob;
    }
}

extern "C" void kernel_launch(void* const* d_in, const int* in_sizes, int n_in,
                              void* d_out, int out_size, void* d_ws, size_t ws_size,
                              hipStream_t stream) {
    const float* x       = (const float*)d_in[0];
    const float* m0_wd   = (const float*)d_in[1];
    const float* m0_ws1  = (const float*)d_in[2];
    const float* m0_bs1  = (const float*)d_in[3];
    const float* m0_wl   = (const float*)d_in[4];
    const float* m0_bl   = (const float*)d_in[5];
    const float* m1_wd   = (const float*)d_in[6];
    const float* m1_ws0  = (const float*)d_in[7];
    const float* m1_bs0  = (const float*)d_in[8];
    const float* m1_ws1  = (const float*)d_in[9];
    const float* m1_bs1  = (const float*)d_in[10];
    const float* m1_wl   = (const float*)d_in[11];
    const float* m1_bl   = (const float*)d_in[12];
    const float* g0_b    = (const float*)d_in[13];
    const float* g1_ws0  = (const float*)d_in[14];
    const float* g1_bs0  = (const float*)d_in[15];
    const float* g1_ws1  = (const float*)d_in[16];
    const float* g1_bs1  = (const float*)d_in[17];
    const float* g1_wl   = (const float*)d_in[18];
    const float* g1_bl   = (const float*)d_in[19];
    float* out = (float*)d_out;

    const int nrows   = in_sizes[0] / 2;      // 1048576
    const int nchunks = nrows / 2;            // float4 chunks (2 rows each)
    const int T       = (nchunks + 1) / 2;    // threads (4 rows each)
    const int threads = 256;
    const int blocks  = (T + threads - 1) / threads;

    hipLaunchKernelGGL(monotone_fused_pk, dim3(blocks), dim3(threads), 0, stream,
                       (const float4*)x, m0_wd, m0_ws1, m0_bs1, m0_wl, m0_bl,
                       m1_wd, m1_ws0, m1_bs0, m1_ws1, m1_bs1, m1_wl, m1_bl,
                       g0_b, g1_ws0, g1_bs0, g1_ws1, g1_bs1, g1_wl, g1_bl,
                       (float4*)out, nchunks, T);
}